// Round 2
// baseline (205.564 us; speedup 1.0000x reference)
//
#include <hip/hip_runtime.h>

// CompanionSSM, one launch: one block (16 waves, 1024 thr) per head.
// G(128x128 bf16) built in LDS; At kept in regs; V/W/ToepK quadrants stored
// as frag-major LDS (4-way-conflict reads); T2 = T@T computed directly
// (one 16x16 tile per wave, 2 MFMAs) and kept f32 in LDS.
// Sequence = 2 rounds x 32 chunks (C=64), 2 chunks per wave per round:
//   Phase A : float4 loads + DPP 4x4 transpose -> U B-frags (regs),
//             R = V@U -> own slots;  pass1 fused (own slots, no barrier):
//             Rsum_g = T@R0 + R1 -> Gsum[w]
//   pass2   : wave 0 scans 16 group summaries with T2 (carry across rounds)
//   pass3+C : seed from Gsum[w]; per chunk Y = Toep@U + W@S (frags from LDS),
//             DPP transpose -> dwordx4 stores; S' = T@S + R
// LDS: 32 slots (64KB, aliases prep G) + Gsum 32KB + T2f 17KB + frags 24KB.

#define NKH 256
#define KD  64
#define SL  4096
#define DM  1024

typedef __attribute__((ext_vector_type(8))) short short8;
typedef __attribute__((ext_vector_type(4))) float floatx4;

#define GSUM_OFF  65536
#define T2_OFF    98304
#define T2_STR    68
#define GKV_OFF   115712
#define GKW_OFF   123904
#define GKK_OFF   132096
#define PHI_OFF   140288
#define KV_OFF    140800
#define LDS_TOTAL 141056

static __device__ __forceinline__ unsigned pack_bf16(float a, float b) {
  union { float f; unsigned u; } ua, ub;
  ua.f = a; ub.f = b;
  return __builtin_amdgcn_perm(ub.u + 0x8000u, ua.u + 0x8000u, 0x07060302u);
}
static __device__ __forceinline__ unsigned short f2bfru(float x) {
  union { float f; unsigned u; } v; v.f = x;
  return (unsigned short)((v.u + 0x8000u) >> 16);
}
static __device__ __forceinline__ float bflo(unsigned d) {
  union { unsigned u; float f; } v; v.u = d << 16; return v.f;
}
static __device__ __forceinline__ float bfhi(unsigned d) {
  union { unsigned u; float f; } v; v.u = d & 0xffff0000u; return v.f;
}
static __device__ __forceinline__ float bf2f(unsigned short s) {
  union { unsigned u; float f; } v; v.u = ((unsigned)s) << 16; return v.f;
}
static __device__ __forceinline__ float wredsum(float x) {
#pragma unroll
  for (int off = 32; off; off >>= 1) x += __shfl_xor(x, off, 64);
  return x;
}
// 4x4 transpose across a DPP quad (lanes 4k..4k+3, c = lane&3).
static __device__ __forceinline__ float4 qtr(float4 v, int c) {
  const bool c1 = (c & 1) != 0, c2 = (c & 2) != 0;
  float a01 = __shfl_xor(v.y, 1, 64), a10 = __shfl_xor(v.x, 1, 64);
  float a23 = __shfl_xor(v.w, 1, 64), a32 = __shfl_xor(v.z, 1, 64);
  float t0 = c1 ? a01 : v.x, t1 = c1 ? v.y : a10;
  float t2 = c1 ? a23 : v.z, t3 = c1 ? v.w : a32;
  float b02 = __shfl_xor(t2, 2, 64), b20 = __shfl_xor(t0, 2, 64);
  float b13 = __shfl_xor(t3, 2, 64), b31 = __shfl_xor(t1, 2, 64);
  float4 r;
  r.x = c2 ? b02 : t0; r.y = c2 ? b13 : t1;
  r.z = c2 ? t2 : b20; r.w = c2 ? t3 : b31;
  return r;
}

// Load chunk starting at row ROW0 (4 batches, 4 channels) as 4 float4/lane.
#define LOADC(ROW0, VA) do { \
  const float* p_ = ubase + (size_t)((ROW0) + tof) * DM; \
  VA[0][0] = *(const float4*)(p_); \
  VA[0][1] = *(const float4*)(p_ + (size_t)4  * DM); \
  VA[1][0] = *(const float4*)(p_ + (size_t)32 * DM); \
  VA[1][1] = *(const float4*)(p_ + (size_t)36 * DM); \
} while (0)

// Transpose chunk J to U B-frags (kept in UB[J]), R = V@U -> own slot J.
#define PROCC(J, VA) do { \
  _Pragma("unroll") \
  for (int kt_ = 0; kt_ < 2; ++kt_) { \
    float4 W0_ = qtr(VA[kt_][0], cc); \
    float4 W1_ = qtr(VA[kt_][1], cc); \
    union { short8 v; unsigned uu[4]; } ub_; \
    ub_.uu[0] = pack_bf16(W0_.x, W0_.y); ub_.uu[1] = pack_bf16(W0_.z, W0_.w); \
    ub_.uu[2] = pack_bf16(W1_.x, W1_.y); ub_.uu[3] = pack_bf16(W1_.z, W1_.w); \
    UB[J][kt_] = ub_.v; \
  } \
  char* slot_ = myslot + (J)*2048; \
  _Pragma("unroll") \
  for (int rt_ = 0; rt_ < 4; ++rt_) { \
    const short8 av0_ = *(const short8*)(GkV + ((rt_*2+0)*64 + lane)*16); \
    const short8 av1_ = *(const short8*)(GkV + ((rt_*2+1)*64 + lane)*16); \
    floatx4 r_ = {0.f, 0.f, 0.f, 0.f}; \
    r_ = __builtin_amdgcn_mfma_f32_16x16x32_bf16(av0_, UB[J][0], r_, 0,0,0); \
    r_ = __builtin_amdgcn_mfma_f32_16x16x32_bf16(av1_, UB[J][1], r_, 0,0,0); \
    uint2 pk_; pk_.x = pack_bf16(r_[0], r_[1]); pk_.y = pack_bf16(r_[2], r_[3]); \
    *(uint2*)(slot_ + rt_*512 + lane*8) = pk_; \
  } \
} while (0)

// One scan step: read R/Rsum (pk) from PTR, optionally write current S over
// it, acc = ATM@S + R, convert C-layout -> B-frags via shfl.
#define SCAN_STEP(PTR, ATM, WRS, WRPK, PKDST) do { \
  uint2 rb_[4]; \
  _Pragma("unroll") \
  for (int rt_ = 0; rt_ < 4; ++rt_) rb_[rt_] = *(const uint2*)((PTR) + rt_*512 + lane*8); \
  if (WRS) { \
    asm volatile("" ::: "memory"); \
    *(short8*)((PTR) + lane*16) = B0; \
    *(short8*)((PTR) + 1024 + lane*16) = B1; \
  } \
  floatx4 acc_[4]; \
  _Pragma("unroll") \
  for (int rt_ = 0; rt_ < 4; ++rt_) { \
    floatx4 cs_; \
    cs_[0] = bflo(rb_[rt_].x); cs_[1] = bfhi(rb_[rt_].x); \
    cs_[2] = bflo(rb_[rt_].y); cs_[3] = bfhi(rb_[rt_].y); \
    floatx4 a0_ = __builtin_amdgcn_mfma_f32_16x16x32_bf16(ATM[rt_][0], B0, cs_, 0,0,0); \
    acc_[rt_]  = __builtin_amdgcn_mfma_f32_16x16x32_bf16(ATM[rt_][1], B1, a0_, 0,0,0); \
  } \
  unsigned pk_[4][2]; \
  _Pragma("unroll") \
  for (int rt_ = 0; rt_ < 4; ++rt_) { \
    pk_[rt_][0] = pack_bf16(acc_[rt_][0], acc_[rt_][1]); \
    pk_[rt_][1] = pack_bf16(acc_[rt_][2], acc_[rt_][3]); \
  } \
  if (WRPK) { \
    _Pragma("unroll") \
    for (int rt_ = 0; rt_ < 4; ++rt_) { \
      uint2 pq_; pq_.x = pk_[rt_][0]; pq_.y = pk_[rt_][1]; \
      *(uint2*)((PKDST) + rt_*512 + lane*8) = pq_; \
    } \
  } \
  { union { short8 v; unsigned uu[4]; } nb0_, nb1_; \
    unsigned xa_, xb_; \
    xa_ = __shfl(pk_[0][0], srcA, 64); xb_ = __shfl(pk_[1][0], srcA, 64); nb0_.uu[0] = hi ? xb_ : xa_; \
    xa_ = __shfl(pk_[0][1], srcA, 64); xb_ = __shfl(pk_[1][1], srcA, 64); nb0_.uu[1] = hi ? xb_ : xa_; \
    xa_ = __shfl(pk_[0][0], srcB, 64); xb_ = __shfl(pk_[1][0], srcB, 64); nb0_.uu[2] = hi ? xb_ : xa_; \
    xa_ = __shfl(pk_[0][1], srcB, 64); xb_ = __shfl(pk_[1][1], srcB, 64); nb0_.uu[3] = hi ? xb_ : xa_; \
    xa_ = __shfl(pk_[2][0], srcA, 64); xb_ = __shfl(pk_[3][0], srcA, 64); nb1_.uu[0] = hi ? xb_ : xa_; \
    xa_ = __shfl(pk_[2][1], srcA, 64); xb_ = __shfl(pk_[3][1], srcA, 64); nb1_.uu[1] = hi ? xb_ : xa_; \
    xa_ = __shfl(pk_[2][0], srcB, 64); xb_ = __shfl(pk_[3][0], srcB, 64); nb1_.uu[2] = hi ? xb_ : xa_; \
    xa_ = __shfl(pk_[2][1], srcB, 64); xb_ = __shfl(pk_[3][1], srcB, 64); nb1_.uu[3] = hi ? xb_ : xa_; \
    B0 = nb0_.v; B1 = nb1_.v; } \
} while (0)

__global__ __launch_bounds__(1024, 4) void fused_kernel(
    const float* __restrict__ u, const float* __restrict__ ga,
    const float* __restrict__ gb, const float* __restrict__ gc,
    float* __restrict__ out)
{
  __shared__ __align__(16) char lds[LDS_TOTAL];
  unsigned short* G = (unsigned short*)lds;     // 128x128 bf16, stride 128
  float* phi = (float*)(lds + PHI_OFF);
  float* kv  = (float*)(lds + KV_OFF);
  float* T2f = (float*)(lds + T2_OFF);          // 64x68 f32
  char* GkV  = lds + GKV_OFF;                   // V frags (frag-major)
  char* GkW  = lds + GKW_OFF;                   // W frags
  char* GkK  = lds + GKK_OFF;                   // Toeplitz frags

  const int i = blockIdx.x;
  const int h = 8 * (i & 31) + (i >> 5);        // consecutive heads same XCD
  const int t = threadIdx.x;
  const int w = t >> 6, lane = t & 63;
  const int n16 = lane & 15, quad = lane >> 4;
  const int bq = (lane >> 2) & 3, cc = lane & 3;

  // ---------------- prep chains (waves 0,1) ----------------
  if (w < 2) {
    const float av = ga[h*KD + lane];
    const float an = av / wredsum(fabsf(av));
    if (w == 1) {
      phi[lane] = gc[h*KD + lane];               // phi[0..63] = c
      float g = an;                              // g_64 = A^64 e0 = a_n
      for (int p = 64; p < 128; ++p) {
        G[(64 + lane)*128 + (p - 64)] = f2bfru(g);   // T col m = g_{64+m}
        const float top = __shfl(g, 63, 64);
        const float gm1 = __shfl_up(g, 1, 64);
        g = (lane > 0 ? gm1 : 0.0f) + an * top;
      }
    } else {
      float v = gb[h*KD + lane];                 // v_j = A^j b
      for (int j = 0; j < KD; ++j) {
        G[(64 + lane)*128 + 64 + (63 - j)] = f2bfru(v);  // V col m = v_{63-m}
        const float top = __shfl(v, 63, 64);
        const float vm1 = __shfl_up(v, 1, 64);
        v = (lane > 0 ? vm1 : 0.0f) + an * top;
      }
    }
  }
  __syncthreads();

  // ------- deferred dot products: phi[64..127] and kv[0..63] -------
  if (t < 128) {
    float acc = 0.f;
    for (int n = 0; n < 64; ++n)
      acc += phi[n] * bf2f(G[(64 + n)*128 + t]);
    if (t < 64) phi[64 + t] = acc;      // phi[p] = c . g_p
    else        kv[127 - t] = acc;      // kv[j] = c . v_j
  }
  __syncthreads();

  // W block: G[j][i] = phi[j+1+i];  Toeplitz: G[j][64+m] = (m<=j)? kv[j-m] : 0
  for (int idx = t; idx < 4096; idx += 1024) {
    const int j = idx >> 6, ii = idx & 63;
    G[j*128 + ii] = f2bfru(phi[j + 1 + ii]);
  }
  for (int idx = t; idx < 4096; idx += 1024) {
    const int j = idx >> 6, m = idx & 63;
    G[j*128 + 64 + m] = (m <= j) ? f2bfru(kv[j - m]) : (unsigned short)0;
  }
  __syncthreads();

  // ---------------- At -> regs; T2 = T@T (one tile/wave); frag copies -----
  short8 At[4][2];
#pragma unroll
  for (int rt = 0; rt < 4; ++rt)
#pragma unroll
    for (int kt = 0; kt < 2; ++kt)
      At[rt][kt] = *(const short8*)(G + (64 + 16*rt + n16)*128 + 32*kt + quad*8);

  {
    const int rt2 = w >> 2, ct2 = w & 3;
    short8 Bt[2];
#pragma unroll
    for (int kt = 0; kt < 2; ++kt) {
      union { short8 v; unsigned short us[8]; } bb;
#pragma unroll
      for (int jj = 0; jj < 8; ++jj)
        bb.us[jj] = G[(64 + 32*kt + 8*quad + jj)*128 + 16*ct2 + n16];
      Bt[kt] = bb.v;
    }
    floatx4 a2 = {0.f, 0.f, 0.f, 0.f};
    a2 = __builtin_amdgcn_mfma_f32_16x16x32_bf16(At[rt2][0], Bt[0], a2, 0,0,0);
    a2 = __builtin_amdgcn_mfma_f32_16x16x32_bf16(At[rt2][1], Bt[1], a2, 0,0,0);
#pragma unroll
    for (int ri = 0; ri < 4; ++ri)
      T2f[(16*rt2 + 4*quad + ri)*T2_STR + 16*ct2 + n16] = a2[ri];
  }

  // frag-major copies: qd0 = V(64,64), qd1 = W(0,0), qd2 = ToepK(0,64)
  for (int idx = t; idx < 1536; idx += 1024) {
    const int qd = idx >> 9, e = idx & 511;
    const int f = e >> 6, l = e & 63;
    const int rt = f >> 1, kt = f & 1;
    const int ln = l & 15, lq = l >> 4;
    const int rowb = (qd == 0) ? 64 : 0;
    const int colb = (qd == 1) ? 0 : 64;
    const unsigned short* src = G + (rowb + 16*rt + ln)*128 + colb + 32*kt + 8*lq;
    *(uint4*)(lds + GKV_OFF + qd*8192 + (f*64 + l)*16) = *(const uint4*)src;
  }
  __syncthreads();   // G dead -> slots usable

  // ---------------- 2 rounds x 32 chunks, 2 chunks per wave ----------------
  const short8 Z8 = {0,0,0,0,0,0,0,0};
  short8 B0c = Z8, B1c = Z8;               // pass2 carry (wave 0)
  const int srcA = n16 + 16*((2*quad) & 3);
  const int srcB = n16 + 16*((2*quad + 1) & 3);
  const bool hi = (quad >= 2);
  const float* ubase = u + (size_t)bq * ((size_t)SL * DM) + 4*h;
  float* obase = out + (size_t)bq * ((size_t)SL * DM) + 4*h;
  const int tof = 8*quad + cc;
  const int rbl = 4*quad + cc;
  char* myslot = lds + w * 4096;           // own 2 slots of 2KB
  char* gsw = lds + GSUM_OFF + w * 2048;

#pragma unroll 1
  for (int r = 0; r < 2; ++r) {
    const int c0 = r*32 + 2*w;             // global chunk index of local j=0

    // ---- Phase A + fused pass1 (own slots only: no barrier needed) ----
    short8 UB[2][2];
    {
      float4 vA[2][2], vB2[2][2];
      LOADC(c0*64, vA);
      LOADC((c0 + 1)*64, vB2);
      PROCC(0, vA);
      PROCC(1, vB2);
    }
    {
      short8 B0 = Z8, B1 = Z8;
      SCAN_STEP(myslot,        At, false, false, myslot);   // B = R0
      SCAN_STEP(myslot + 2048, At, false, true,  gsw);      // Rsum -> Gsum[w]
    }
    __syncthreads();

    // ---- pass2: wave 0 scans 16 group summaries with T2 ----
    if (w == 0) {
      short8 At2[4][2];
#pragma unroll
      for (int rt = 0; rt < 4; ++rt)
#pragma unroll
        for (int kt = 0; kt < 2; ++kt) {
          union { short8 v; unsigned short us[8]; } ua;
          const float* sp2 = T2f + (16*rt + n16)*T2_STR + 32*kt + 8*quad;
#pragma unroll
          for (int jj = 0; jj < 8; ++jj) ua.us[jj] = (short)f2bfru(sp2[jj]);
          At2[rt][kt] = ua.v;
        }
      short8 B0 = B0c, B1 = B1c;
#pragma unroll 1
      for (int g = 0; g < 16; ++g) {
        char* gp = lds + GSUM_OFF + g*2048;
        SCAN_STEP(gp, At2, true, false, gp);   // reads Rsum_g, writes S_g
      }
      B0c = B0; B1c = B1;
    }
    __syncthreads();

    // ---- pass3 + Phase C fused ----
    {
      short8 B0 = *(const short8*)(gsw + lane*16);
      short8 B1 = *(const short8*)(gsw + 1024 + lane*16);
#pragma unroll
      for (int j = 0; j < 2; ++j) {
        char* sp = myslot + j*2048;
#pragma unroll
        for (int rt = 0; rt < 4; ++rt) {
          const short8 ap0 = *(const short8*)(GkK + ((rt*2+0)*64 + lane)*16);
          const short8 ap1 = *(const short8*)(GkK + ((rt*2+1)*64 + lane)*16);
          const short8 aw0 = *(const short8*)(GkW + ((rt*2+0)*64 + lane)*16);
          const short8 aw1 = *(const short8*)(GkW + ((rt*2+1)*64 + lane)*16);
          floatx4 ty = {0.f, 0.f, 0.f, 0.f};
          ty = __builtin_amdgcn_mfma_f32_16x16x32_bf16(ap0, UB[j][0], ty, 0,0,0);
          ty = __builtin_amdgcn_mfma_f32_16x16x32_bf16(ap1, UB[j][1], ty, 0,0,0);
          ty = __builtin_amdgcn_mfma_f32_16x16x32_bf16(aw0, B0,       ty, 0,0,0);
          ty = __builtin_amdgcn_mfma_f32_16x16x32_bf16(aw1, B1,       ty, 0,0,0);
          float4 yv; yv.x = ty[0]; yv.y = ty[1]; yv.z = ty[2]; yv.w = ty[3];
          float4 tw = qtr(yv, cc);
          *(float4*)(obase + (size_t)((c0 + j)*64 + 16*rt + rbl) * DM) = tw;
        }
        SCAN_STEP(sp, At, false, false, sp);   // S' = T@S + R
      }
    }
    // no barrier needed: next round touches only own slots until pass2,
    // which is ordered by the post-pass1 barrier.
  }
}

// ---------------------------------------------------------------- launch --
extern "C" void kernel_launch(void* const* d_in, const int* in_sizes, int n_in,
                              void* d_out, int out_size, void* d_ws, size_t ws_size,
                              hipStream_t stream)
{
  const float* u = (const float*)d_in[0];
  const float* a = (const float*)d_in[1];
  const float* b = (const float*)d_in[2];
  const float* c = (const float*)d_in[3];
  float* out = (float*)d_out;
  (void)d_ws; (void)ws_size; (void)in_sizes; (void)n_in; (void)out_size;

  fused_kernel<<<NKH, 1024, 0, stream>>>(u, a, b, c, out);
}

// Round 3
// 197.810 us; speedup vs baseline: 1.0392x; 1.0392x over previous
//
#include <hip/hip_runtime.h>

// CompanionSSM, one launch: one block (8 waves, 512 thr) per (head-group of 4
// heads) x (1 batch).  Per-row footprint = 16 channels x 4B = 64B contiguous
// -> every global load/store is full-line (16 rows x 64B per instruction).
// Per-head G quadrants (V, W, ToepK) stored frag-major in LDS (lane-linear
// conflict-free reads); T-frags in registers.  R/scan/Y MFMAs issued per-head
// (4x) with per-lane column select (head of column n16 = n16>>2).
// Proven round-0 schedule: 4 quarters x 16 chunks, Phase A (own slots) ->
// barrier -> Phase B (wave 0 serial scan, shfl C->B-frag) -> barrier ->
// Phase C (Y = Toep@U + W@S, qtr transpose, float4 stores).
// LDS: V/W/K frags 96KB + 16 slots 32KB (prep-aliased: T-frag temp) + phi/kv.

#define NKH 256
#define KD  64
#define SL  4096
#define DM  1024

typedef __attribute__((ext_vector_type(8))) short short8;
typedef __attribute__((ext_vector_type(4))) float floatx4;

#define VOFF      0
#define WOFF      32768
#define KOFF      65536
#define SLOTS_OFF 98304
#define PHI_OFF   131072
#define KV_OFF    133120
#define LDS_TOTAL 134144

static __device__ __forceinline__ unsigned pack_bf16(float a, float b) {
  union { float f; unsigned u; } ua, ub;
  ua.f = a; ub.f = b;
  return __builtin_amdgcn_perm(ub.u + 0x8000u, ua.u + 0x8000u, 0x07060302u);
}
static __device__ __forceinline__ unsigned short f2bfru(float x) {
  union { float f; unsigned u; } v; v.f = x;
  return (unsigned short)((v.u + 0x8000u) >> 16);
}
static __device__ __forceinline__ float bflo(unsigned d) {
  union { unsigned u; float f; } v; v.u = d << 16; return v.f;
}
static __device__ __forceinline__ float bfhi(unsigned d) {
  union { unsigned u; float f; } v; v.u = d & 0xffff0000u; return v.f;
}
static __device__ __forceinline__ float wredsum(float x) {
#pragma unroll
  for (int off = 32; off; off >>= 1) x += __shfl_xor(x, off, 64);
  return x;
}
// 4x4 transpose across a DPP quad (lanes 4k..4k+3, c = lane&3).
static __device__ __forceinline__ float4 qtr(float4 v, int c) {
  const bool c1 = (c & 1) != 0, c2 = (c & 2) != 0;
  float a01 = __shfl_xor(v.y, 1, 64), a10 = __shfl_xor(v.x, 1, 64);
  float a23 = __shfl_xor(v.w, 1, 64), a32 = __shfl_xor(v.z, 1, 64);
  float t0 = c1 ? a01 : v.x, t1 = c1 ? v.y : a10;
  float t2 = c1 ? a23 : v.z, t3 = c1 ? v.w : a32;
  float b02 = __shfl_xor(t2, 2, 64), b20 = __shfl_xor(t0, 2, 64);
  float b13 = __shfl_xor(t3, 2, 64), b31 = __shfl_xor(t1, 2, 64);
  float4 r;
  r.x = c2 ? b02 : t0; r.y = c2 ? b13 : t1;
  r.z = c2 ? t2 : b20; r.w = c2 ? t3 : b31;
  return r;
}
// per-lane 4-way select (column ch uses head ch>>2)
static __device__ __forceinline__ floatx4 sel4(floatx4 a, floatx4 b,
                                               floatx4 c, floatx4 d, int hs) {
  floatx4 r;
#pragma unroll
  for (int k = 0; k < 4; ++k) {
    const float x = (hs & 1) ? b[k] : a[k];
    const float y = (hs & 1) ? d[k] : c[k];
    r[k] = (hs & 2) ? y : x;
  }
  return r;
}
// frag-major 16B-group byte offset for 64x64 bf16: element (row, colg..colg+7)
static __device__ __forceinline__ int fmoff(int row, int colg) {
  return ((((row >> 4) * 2 + (colg >> 5)) * 64 + ((colg >> 3) & 3) * 16 + (row & 15)) << 4);
}

__global__ __launch_bounds__(512, 1) void fused_kernel(
    const float* __restrict__ u, const float* __restrict__ ga,
    const float* __restrict__ gb, const float* __restrict__ gc,
    float* __restrict__ out)
{
  __shared__ __align__(16) char lds[LDS_TOTAL];
  float* phi = (float*)(lds + PHI_OFF);   // f32[4][128]
  float* kv  = (float*)(lds + KV_OFF);    // f32[4][64]

  const int i = blockIdx.x;
  const int hg = i >> 2, bq = i & 3;      // head-group, batch
  const int t = threadIdx.x;
  const int w = t >> 6, lane = t & 63;
  const int n16 = lane & 15, quad = lane >> 4;
  const int cq = n16 >> 2, cj = n16 & 3;  // channel-quarter (= head), sub-ch

  // ---------------- prep chains: wave w -> head w>>1, role w&1 ----------------
  {
    const int hw = w >> 1, role = w & 1;
    const int gh = 4*hg + hw;
    const float av = ga[gh*KD + lane];
    const float an = av / wredsum(fabsf(av));   // mean(|rowsum|) >> eps
    const float cv = gc[gh*KD + lane];
    if (role) {
      phi[hw*128 + lane] = cv;                  // phi_p = c_p for p<64
      float g = an;                             // g_64 = A^64 e0 = a_n
      union { short8 v; unsigned short us[8]; } g8;
      for (int p = 64; p < 128; ++p) {
        g8.us[p & 7] = f2bfru(g);               // T col (p-64), row = lane
        if ((p & 7) == 7)
          *(short8*)(lds + SLOTS_OFF + hw*8192 + fmoff(lane, (p - 64) & ~7)) = g8.v;
        const float d = wredsum(cv * g);
        if (lane == 0) phi[hw*128 + p] = d;
        const float top = __shfl(g, 63, 64);
        const float gm1 = __shfl_up(g, 1, 64);
        g = (lane > 0 ? gm1 : 0.0f) + an * top;
      }
    } else {
      float v = gb[gh*KD + lane];               // v_j = A^j b
      union { short8 v8; unsigned short us[8]; } v8u;
      for (int j = 0; j < KD; ++j) {
        const float d = wredsum(cv * v);
        if (lane == 0) kv[hw*64 + j] = d;       // k[j] = c.v_j
        const int col = 63 - j;                 // V col m = v_{63-m}
        v8u.us[col & 7] = f2bfru(v);
        if ((col & 7) == 0)
          *(short8*)(lds + VOFF + hw*8192 + fmoff(lane, col)) = v8u.v8;
        const float top = __shfl(v, 63, 64);
        const float vm1 = __shfl_up(v, 1, 64);
        v = (lane > 0 ? vm1 : 0.0f) + an * top;
      }
    }
  }
  __syncthreads();

  // ---------------- W/K frag fills + T-frag extraction ----------------
  // W[j][i] = phi[j+1+i];  K[j][m] = (m<=j) ? kv[j-m] : 0
  for (int idx = t; idx < 2048; idx += 512) {
    const int h = idx >> 9, g2 = idx & 511;
    const int cgi = g2 >> 6, row = g2 & 63;
    const int colg = cgi * 8;
    union { short8 v; unsigned short us[8]; } wb, kb;
#pragma unroll
    for (int jj = 0; jj < 8; ++jj) {
      wb.us[jj] = f2bfru(phi[h*128 + row + 1 + colg + jj]);
      const int m = colg + jj;
      kb.us[jj] = (m <= row) ? f2bfru(kv[h*64 + row - m]) : (unsigned short)0;
    }
    *(short8*)(lds + WOFF + h*8192 + fmoff(row, colg)) = wb.v;
    *(short8*)(lds + KOFF + h*8192 + fmoff(row, colg)) = kb.v;
  }
  short8 At[4][4][2];
#pragma unroll
  for (int h = 0; h < 4; ++h)
#pragma unroll
    for (int rt = 0; rt < 4; ++rt)
#pragma unroll
      for (int kt = 0; kt < 2; ++kt)
        At[h][rt][kt] = *(const short8*)(lds + SLOTS_OFF + h*8192 +
                                         (((rt*2 + kt)*64 + lane) << 4));
  __syncthreads();   // T temp dead -> slots usable

  // ---------------- main: 4 quarters x 16 chunks ----------------
  const float* ubase = u  + (size_t)bq * ((size_t)SL * DM) + hg*16 + cq*4;
  float*       obase = out + (size_t)bq * ((size_t)SL * DM) + hg*16 + cq*4;
  const int srcA = n16 + 16*((2*quad) & 3);
  const int srcB = n16 + 16*((2*quad + 1) & 3);
  const bool hi = (quad >= 2);
  const short8 Z8 = {0,0,0,0,0,0,0,0};
  short8 B0 = Z8, B1 = Z8;                // scan carry (wave 0)

#pragma unroll 1
  for (int Q = 0; Q < 4; ++Q) {
    const int q0 = Q * 16;
    short8 UB[2][2];

    // ---- Phase A: 2 chunks/wave; full-line float4 loads + qtr transpose ----
    {
      float4 L[2][2][2];   // [s][kt][hf]
#pragma unroll
      for (int s = 0; s < 2; ++s) {
        const int qg = q0 + w + 8*s;
#pragma unroll
        for (int kt = 0; kt < 2; ++kt)
#pragma unroll
          for (int hf = 0; hf < 2; ++hf)
            L[s][kt][hf] = *(const float4*)(ubase +
                (size_t)(qg*64 + 32*kt + 8*quad + 4*hf + cj) * DM);
      }
#pragma unroll
      for (int s = 0; s < 2; ++s) {
        const int lq = w + 8*s;
#pragma unroll
        for (int kt = 0; kt < 2; ++kt) {
          float4 W0 = qtr(L[s][kt][0], cj);
          float4 W1 = qtr(L[s][kt][1], cj);
          union { short8 v; unsigned uu[4]; } ub;
          ub.uu[0] = pack_bf16(W0.x, W0.y); ub.uu[1] = pack_bf16(W0.z, W0.w);
          ub.uu[2] = pack_bf16(W1.x, W1.y); ub.uu[3] = pack_bf16(W1.z, W1.w);
          UB[s][kt] = ub.v;
        }
        char* slot = lds + SLOTS_OFF + lq*2048;
#pragma unroll
        for (int rt = 0; rt < 4; ++rt) {
          floatx4 rh[4];
#pragma unroll
          for (int h = 0; h < 4; ++h) {
            const short8 v0 = *(const short8*)(lds + VOFF + h*8192 + (((rt*2+0)*64 + lane) << 4));
            const short8 v1 = *(const short8*)(lds + VOFF + h*8192 + (((rt*2+1)*64 + lane) << 4));
            floatx4 acc = {0.f, 0.f, 0.f, 0.f};
            acc   = __builtin_amdgcn_mfma_f32_16x16x32_bf16(v0, UB[s][0], acc, 0,0,0);
            rh[h] = __builtin_amdgcn_mfma_f32_16x16x32_bf16(v1, UB[s][1], acc, 0,0,0);
          }
          floatx4 r = sel4(rh[0], rh[1], rh[2], rh[3], cq);
          uint2 pk; pk.x = pack_bf16(r[0], r[1]); pk.y = pack_bf16(r[2], r[3]);
          *(uint2*)(slot + rt*512 + lane*8) = pk;
        }
      }
    }
    __syncthreads();

    // ---- Phase B: wave 0 serial scan; slots <- entering S ----
    if (w == 0) {
#pragma unroll 1
      for (int lq = 0; lq < 16; ++lq) {
        char* sp = lds + SLOTS_OFF + lq*2048;
        uint2 rb[4];
#pragma unroll
        for (int rt = 0; rt < 4; ++rt) rb[rt] = *(const uint2*)(sp + rt*512 + lane*8);
        asm volatile("" ::: "memory");
        *(short8*)(sp + lane*16)        = B0;
        *(short8*)(sp + 1024 + lane*16) = B1;
        unsigned pk[4][2];
#pragma unroll
        for (int rt = 0; rt < 4; ++rt) {
          floatx4 cs;
          cs[0] = bflo(rb[rt].x); cs[1] = bfhi(rb[rt].x);
          cs[2] = bflo(rb[rt].y); cs[3] = bfhi(rb[rt].y);
          floatx4 ah[4];
#pragma unroll
          for (int h = 0; h < 4; ++h) {
            floatx4 a0 = __builtin_amdgcn_mfma_f32_16x16x32_bf16(At[h][rt][0], B0, cs, 0,0,0);
            ah[h]      = __builtin_amdgcn_mfma_f32_16x16x32_bf16(At[h][rt][1], B1, a0, 0,0,0);
          }
          floatx4 acc = sel4(ah[0], ah[1], ah[2], ah[3], cq);
          pk[rt][0] = pack_bf16(acc[0], acc[1]);
          pk[rt][1] = pack_bf16(acc[2], acc[3]);
        }
        union { short8 v; unsigned uu[4]; } nb0, nb1;
        unsigned xa, xb;
        xa = __shfl(pk[0][0], srcA, 64); xb = __shfl(pk[1][0], srcA, 64); nb0.uu[0] = hi ? xb : xa;
        xa = __shfl(pk[0][1], srcA, 64); xb = __shfl(pk[1][1], srcA, 64); nb0.uu[1] = hi ? xb : xa;
        xa = __shfl(pk[0][0], srcB, 64); xb = __shfl(pk[1][0], srcB, 64); nb0.uu[2] = hi ? xb : xa;
        xa = __shfl(pk[0][1], srcB, 64); xb = __shfl(pk[1][1], srcB, 64); nb0.uu[3] = hi ? xb : xa;
        xa = __shfl(pk[2][0], srcA, 64); xb = __shfl(pk[3][0], srcA, 64); nb1.uu[0] = hi ? xb : xa;
        xa = __shfl(pk[2][1], srcA, 64); xb = __shfl(pk[3][1], srcA, 64); nb1.uu[1] = hi ? xb : xa;
        xa = __shfl(pk[2][0], srcB, 64); xb = __shfl(pk[3][0], srcB, 64); nb1.uu[2] = hi ? xb : xa;
        xa = __shfl(pk[2][1], srcB, 64); xb = __shfl(pk[3][1], srcB, 64); nb1.uu[3] = hi ? xb : xa;
        B0 = nb0.v; B1 = nb1.v;
      }
    }
    __syncthreads();

    // ---- Phase C: Y = Toep@U + W@S; qtr transpose; full-line stores ----
#pragma unroll
    for (int s = 0; s < 2; ++s) {
      const int lq = w + 8*s;
      const int qg = q0 + lq;
      char* sp = lds + SLOTS_OFF + lq*2048;
      const short8 S0 = *(const short8*)(sp + lane*16);
      const short8 S1 = *(const short8*)(sp + 1024 + lane*16);
#pragma unroll
      for (int rt = 0; rt < 4; ++rt) {
        floatx4 th[4];
#pragma unroll
        for (int h = 0; h < 4; ++h) {
          const short8 k0 = *(const short8*)(lds + KOFF + h*8192 + (((rt*2+0)*64 + lane) << 4));
          const short8 k1 = *(const short8*)(lds + KOFF + h*8192 + (((rt*2+1)*64 + lane) << 4));
          const short8 w0 = *(const short8*)(lds + WOFF + h*8192 + (((rt*2+0)*64 + lane) << 4));
          const short8 w1 = *(const short8*)(lds + WOFF + h*8192 + (((rt*2+1)*64 + lane) << 4));
          floatx4 ty = {0.f, 0.f, 0.f, 0.f};
          ty    = __builtin_amdgcn_mfma_f32_16x16x32_bf16(k0, UB[s][0], ty, 0,0,0);
          ty    = __builtin_amdgcn_mfma_f32_16x16x32_bf16(k1, UB[s][1], ty, 0,0,0);
          ty    = __builtin_amdgcn_mfma_f32_16x16x32_bf16(w0, S0,       ty, 0,0,0);
          th[h] = __builtin_amdgcn_mfma_f32_16x16x32_bf16(w1, S1,       ty, 0,0,0);
        }
        floatx4 ty = sel4(th[0], th[1], th[2], th[3], cq);
        float4 yv; yv.x = ty[0]; yv.y = ty[1]; yv.z = ty[2]; yv.w = ty[3];
        float4 tw = qtr(yv, cj);
        *(float4*)(obase + (size_t)(qg*64 + 16*rt + 4*quad + cj) * DM) = tw;
      }
    }
    // no barrier: next Phase A touches only this wave's own slots, and
    // Phase B(Q+1) is ordered by the post-A barrier.
  }
}

// ---------------------------------------------------------------- launch --
extern "C" void kernel_launch(void* const* d_in, const int* in_sizes, int n_in,
                              void* d_out, int out_size, void* d_ws, size_t ws_size,
                              hipStream_t stream)
{
  const float* u = (const float*)d_in[0];
  const float* a = (const float*)d_in[1];
  const float* b = (const float*)d_in[2];
  const float* c = (const float*)d_in[3];
  float* out = (float*)d_out;
  (void)d_ws; (void)ws_size; (void)in_sizes; (void)n_in; (void)out_size;

  fused_kernel<<<NKH, 512, 0, stream>>>(u, a, b, c, out);
}